// Round 1
// baseline (668.992 us; speedup 1.0000x reference)
//
#include <hip/hip_runtime.h>
#include <hip/hip_bf16.h>

// SumPooling / segment_sum: out[s, d] = sum_{i: index[i]==s} x[i, d]
// x: (1e6, 128) fp32, index: (1e6,) sorted int, out: (16384, 128) fp32.
// Strategy: one 64-lane wave per contiguous 128-row chunk; lane holds a
// float2 column slice; run-length accumulate in registers (index sorted),
// atomicAdd only at segment boundaries / chunk edges.

constexpr int D_FEAT = 128;
constexpr int D2 = D_FEAT / 2;            // float2 elements per row = 64
constexpr int ROWS_PER_WAVE = 128;
constexpr int WAVES_PER_BLOCK = 4;        // block = 256 threads

__global__ void zero_out_kernel(float4* __restrict__ out, int n4) {
    int i = blockIdx.x * blockDim.x + threadIdx.x;
    int stride = gridDim.x * blockDim.x;
    for (; i < n4; i += stride) {
        out[i] = make_float4(0.f, 0.f, 0.f, 0.f);
    }
}

__global__ __launch_bounds__(256) void segsum_kernel(
        const float* __restrict__ x,
        const int* __restrict__ index,
        float* __restrict__ out,
        int n_rows) {
    const int wave_in_block = threadIdx.x >> 6;
    const int lane = threadIdx.x & 63;
    const long wave = (long)blockIdx.x * WAVES_PER_BLOCK + wave_in_block;

    long row0 = wave * ROWS_PER_WAVE;
    if (row0 >= n_rows) return;
    long rend = row0 + ROWS_PER_WAVE;
    if (rend > n_rows) rend = n_rows;

    const float2* __restrict__ x2 = (const float2*)x;

    float2 acc = make_float2(0.f, 0.f);
    int cur_seg = index[row0];

    for (long r = row0; r < rend; ++r) {
        int s = index[r];                       // uniform across the wave
        float2 v = x2[r * D2 + lane];           // coalesced 8B/lane
        if (s != cur_seg) {                     // wave-uniform branch
            float* o = out + (long)cur_seg * D_FEAT + 2 * lane;
            atomicAdd(o, acc.x);
            atomicAdd(o + 1, acc.y);
            cur_seg = s;
            acc = v;
        } else {
            acc.x += v.x;
            acc.y += v.y;
        }
    }
    float* o = out + (long)cur_seg * D_FEAT + 2 * lane;
    atomicAdd(o, acc.x);
    atomicAdd(o + 1, acc.y);
}

extern "C" void kernel_launch(void* const* d_in, const int* in_sizes, int n_in,
                              void* d_out, int out_size, void* d_ws, size_t ws_size,
                              hipStream_t stream) {
    const float* x = (const float*)d_in[0];
    const int* index = (const int*)d_in[1];
    float* out = (float*)d_out;

    const int n_rows = in_sizes[1];           // 1,000,000
    const int n_out4 = out_size / 4;          // out_size = 16384*128

    // Zero the (poisoned) output first.
    zero_out_kernel<<<256, 256, 0, stream>>>((float4*)out, n_out4);

    const long n_waves = ((long)n_rows + ROWS_PER_WAVE - 1) / ROWS_PER_WAVE;
    const int n_blocks = (int)((n_waves + WAVES_PER_BLOCK - 1) / WAVES_PER_BLOCK);
    segsum_kernel<<<n_blocks, 256, 0, stream>>>(x, index, out, n_rows);
}